// Round 15
// baseline (128.994 us; speedup 1.0000x reference)
//
#include <hip/hip_runtime.h>

namespace {
constexpr int B = 2, C = 72, O = 72, H = 180, W = 320;
constexpr int K = 9, G = 9, Cg = 8, Og = 8;
constexpr int OFFC = 2 * K;           // 18 offset channels
constexpr int HW = H * W;             // 57600
constexpr size_t OFF_ELEMS = (size_t)B * OFFC * HW;   // 2,073,600 floats
constexpr int W1_ELEMS = OFFC * C * 9;                // 11664
constexpr int W2_ELEMS = O * Cg * 9;                  // 5184
constexpr int ICW = C / 4;            // 18 input channels per wave

// deform tile geometry: one block = one group x (64 wide x 4 tall) pixels
constexpr int TW = 64, TH = 4;
constexpr int HALO = 2;               // R7-validated; global fallback for tail
constexpr int NR = TH + 2 * HALO;     // 8 staged rows
constexpr int NC = TW + 2 * HALO;     // 68 staged cols
constexpr int TX = W / TW;            // 5
constexpr int TY = H / TH;            // 45

typedef float f2u __attribute__((ext_vector_type(2), aligned(4)));
}

// ---------------------------------------------------------------------------
// Setup: transpose weights for contiguous wave-uniform (scalar) access.
//   w1t[ic][tap][oc]   <- off_w[oc][ic][tap]
//   w2t[g][k][cg][og]  <- weight[g*8+og][cg][k]
// ---------------------------------------------------------------------------
__global__ __launch_bounds__(256) void transpose_weights(
    const float* __restrict__ off_w,
    const float* __restrict__ weight,
    float* __restrict__ w1t,
    float* __restrict__ w2t)
{
    int i = blockIdx.x * blockDim.x + threadIdx.x;
    if (i < W1_ELEMS) {
        int oc = i % OFFC;
        int tap = (i / OFFC) % 9;
        int ic = i / (OFFC * 9);
        w1t[i] = off_w[(oc * C + ic) * 9 + tap];
    }
    if (i < W2_ELEMS) {
        int og = i % Og;
        int cg = (i / Og) % Cg;
        int k = (i / (Og * Cg)) % K;
        int g = i / (Og * Cg * K);
        w2t[i] = weight[((g * Og + og) * Cg + cg) * 9 + k];
    }
}

// ---------------------------------------------------------------------------
// Kernel 1: 3x3 conv (C=72 -> 18) + bias. 4 waves split C; LDS reduce.
// R15 = R14's neighbor-sharing with __shfl_up/__shfl_down (unambiguous
// semantics; R14's raw DPP wave-shift had the direction wrong -> absmax
// fail). Per (ic,ky): ONE coalesced row load; neighbors via
// __shfl_up(v,1) (pixel xw-1) / __shfl_down(v,1) (pixel xw+1); lanes 0/63
// patched from 2 block-uniform halo scalars (zeroed at image edges).
// VMEM per thread 162 -> 54. FMA loop / LDS reduce unchanged from R9.
// ---------------------------------------------------------------------------
__global__ __launch_bounds__(256) void offset_conv(
    const float* __restrict__ x,
    const float* __restrict__ w1t,
    const float* __restrict__ bias,
    float* __restrict__ offs)
{
    __shared__ float red[4 * 64 * OFFC];
    const int lane = threadIdx.x & 63;
    const int wave = threadIdx.x >> 6;

    const int g0 = blockIdx.x * 64;
    const int b = g0 / HW;
    const int pix = g0 - b * HW;
    const int yh = pix / W;
    const int x0b = pix - yh * W;
    const int xw = x0b + lane;

    float acc[OFFC];
    #pragma unroll
    for (int oc = 0; oc < OFFC; ++oc) acc[oc] = 0.f;

    const float* xb = x + (size_t)b * C * HW;
    const int ic0 = __builtin_amdgcn_readfirstlane(wave * ICW);

    const bool rv0 = (yh - 1) >= 0;
    const bool rv2 = (yh + 1) < H;

    // block-uniform halo columns (clamped addresses; value zeroed at edges)
    const bool has_l = (x0b > 0);
    const bool has_r = (x0b + 64 < W);
    const int sxl = has_l ? (x0b - 1) : 0;
    const int sxr = has_r ? (x0b + 64) : (W - 1);
    const bool lane0 = (lane == 0);
    const bool lane63 = (lane == 63);

    #pragma unroll 3
    for (int ici = 0; ici < ICW; ++ici) {
        const int ic = ic0 + ici;
        const float* xc = xb + ic * HW;
        #pragma unroll
        for (int ky = 0; ky < 3; ++ky) {
            const int yy = yh + ky - 1;
            const bool rowv = (ky == 0) ? rv0 : (ky == 2 ? rv2 : true);
            if (!rowv) continue;           // uniform branch
            const float* xr = xc + yy * W;
            const float v = xr[xw];                      // 1 coalesced load
            const float slr = xr[sxl];                   // uniform addr
            const float srr = xr[sxr];                   // uniform addr
            const float sl = has_l ? slr : 0.f;          // uniform select
            const float sr = has_r ? srr : 0.f;
            float vm1 = __shfl_up(v, 1);                 // lane l-1 = xw-1
            float vp1 = __shfl_down(v, 1);               // lane l+1 = xw+1
            vm1 = lane0 ? sl : vm1;
            vp1 = lane63 ? sr : vp1;
            const float* wp = w1t + (ic * 9 + ky * 3) * OFFC;
            #pragma unroll
            for (int oc = 0; oc < OFFC; ++oc)
                acc[oc] = fmaf(vm1, wp[oc], acc[oc]);
            #pragma unroll
            for (int oc = 0; oc < OFFC; ++oc)
                acc[oc] = fmaf(v, wp[OFFC + oc], acc[oc]);
            #pragma unroll
            for (int oc = 0; oc < OFFC; ++oc)
                acc[oc] = fmaf(vp1, wp[2 * OFFC + oc], acc[oc]);
        }
    }

    #pragma unroll
    for (int oc = 0; oc < OFFC; ++oc)
        red[(wave * 64 + lane) * OFFC + oc] = acc[oc];
    __syncthreads();

    for (int e = threadIdx.x; e < 64 * OFFC; e += 256) {
        const int oc = e / 64;
        const int px = e - oc * 64;
        float s = bias[oc];
        #pragma unroll
        for (int w = 0; w < 4; ++w)
            s += red[(w * 64 + px) * OFFC + oc];
        offs[(size_t)b * OFFC * HW + (size_t)oc * HW + pix + px] = s;
    }
}

// ---------------------------------------------------------------------------
// Kernel 2: deformable grouped conv, LDS-staged. EXACT R11 version (52us,
// VGPR 36): interior path batches 4 channels' LDS reads into temp register
// arrays before the 48 FMAs. R12's pk-fma asm variant was slower — rejected.
// ---------------------------------------------------------------------------
__global__ __launch_bounds__(256) void deform_conv(
    const float* __restrict__ x,      // (B, C, H, W)
    const float* __restrict__ offs,   // (B, 18, H, W)
    const float* __restrict__ w2t,    // [g][k][cg][og]
    float* __restrict__ out)          // (B, O, H, W)
{
    __shared__ float sm[Cg * NR * NC];     // 17,408 B

    const int bi = blockIdx.x;
    const int tx = bi % TX;
    const int ty = (bi / TX) % TY;
    const int g  = (bi / (TX * TY)) % G;
    const int b  = bi / (TX * TY * G);

    const int lane = threadIdx.x & 63;
    const int wave = threadIdx.x >> 6;
    const int xw = tx * TW + lane;
    const int yh = ty * TH + wave;

    const int gu = __builtin_amdgcn_readfirstlane(g);
    const float* wg = w2t + gu * (K * Cg * Og);
    const float* xg = x + ((size_t)b * C + gu * Cg) * HW;
    const float* offp = offs + (size_t)b * OFFC * HW + yh * W + xw;

    // Hoist offset loads (in flight while we stage).
    float dy[K], dx[K];
    #pragma unroll
    for (int k = 0; k < K; ++k) {
        dy[k] = offp[(size_t)(2 * k) * HW];
        dx[k] = offp[(size_t)(2 * k + 1) * HW];
    }

    // Stage window [wy, wy+NR) x [wx, wx+NC) for 8 channels (div/mod-free).
    const int wy = ty * TH - HALO;
    const int wx = tx * TW - HALO;
    {
        const int sxl = min(max(wx + lane, 0), W - 1);   // per-lane, once
        #pragma unroll
        for (int i = 0; i < 16; ++i) {
            const int rowi = 4 * i + wave;               // 0..63, wave-uniform
            const int ch = rowi >> 3;
            const int rr = rowi & 7;
            const int sy = min(max(wy + rr, 0), H - 1);  // wave-uniform (SALU)
            sm[rowi * NC + lane] = xg[ch * HW + sy * W + sxl];
        }
        // tail cols 64..67: thread t -> row t>>2, col 64+(t&3)
        const int rowt = threadIdx.x >> 2;
        const int ct = 64 + (threadIdx.x & 3);
        const int cht = rowt >> 3;
        const int rrt = rowt & 7;
        const int syt = min(max(wy + rrt, 0), H - 1);
        const int sxt = min(max(wx + ct, 0), W - 1);
        sm[rowt * NC + ct] = xg[cht * HW + syt * W + sxt];
    }
    __syncthreads();

    float acc[Og];
    #pragma unroll
    for (int og = 0; og < Og; ++og) acc[og] = 0.f;

    #pragma unroll
    for (int k = 0; k < K; ++k) {
        float py = (float)(yh + k / 3 - 1) + dy[k];
        float px = (float)(xw + k % 3 - 1) + dx[k];
        float fy = floorf(py);
        float fx = floorf(px);
        int y0 = (int)fy, x0 = (int)fx;
        float wy1 = py - fy, wx1 = px - fx;
        float wy0 = 1.f - wy1, wx0 = 1.f - wx1;

        float w00, w01, w10, w11;
        int lr0, lr1, lcb, r0, r1;
        if (__all((y0 >= 0) & (y0 + 1 < H) & (x0 >= 0) & (x0 + 1 < W))) {
            // fully interior wave: no clamp/validity logic needed
            w00 = wy0 * wx0; w01 = wy0 * wx1;
            w10 = wy1 * wx0; w11 = wy1 * wx1;
            lr0 = y0 - wy; lr1 = lr0 + 1; lcb = x0 - wx;
            r0 = y0 * W + x0; r1 = r0 + W;
        } else {
            float hy0 = ((y0 >= 0) & (y0 < H)) ? wy0 : 0.f;
            float hy1 = ((y0 + 1 >= 0) & (y0 + 1 < H)) ? wy1 : 0.f;
            float gx0 = ((x0 >= 0) & (x0 < W)) ? wx0 : 0.f;
            float gx1 = ((x0 + 1 >= 0) & (x0 + 1 < W)) ? wx1 : 0.f;
            int y0c = min(max(y0, 0), H - 1);
            int y1c = min(max(y0 + 1, 0), H - 1);
            int x0c = min(max(x0, 0), W - 1);
            int x1c = min(max(x0 + 1, 0), W - 1);
            int xb2 = min(max(x0, 0), W - 2);
            float wA = (x0c == xb2 ? gx0 : 0.f) + (x1c == xb2 ? gx1 : 0.f);
            float wB = (x0c == xb2 + 1 ? gx0 : 0.f) + (x1c == xb2 + 1 ? gx1 : 0.f);
            w00 = hy0 * wA; w01 = hy0 * wB;
            w10 = hy1 * wA; w11 = hy1 * wB;
            lr0 = y0c - wy; lr1 = y1c - wy; lcb = xb2 - wx;
            r0 = y0c * W + xb2; r1 = y1c * W + xb2;
        }
        const bool inw = ((unsigned)lr0 < NR) & ((unsigned)lr1 < NR) &
                         ((unsigned)lcb < (NC - 1));
        const float* wk = wg + k * (Cg * Og);

        if (inw) {
            const float* s0 = sm + lr0 * NC + lcb;
            const float* s1 = sm + lr1 * NC + lcb;
            #pragma unroll
            for (int h = 0; h < 2; ++h) {           // 2 batches of 4 channels
                float t00[4], t01[4], t10[4], t11[4];
                #pragma unroll
                for (int j = 0; j < 4; ++j) {       // issue 16 ds_reads
                    const int o = (4 * h + j) * (NR * NC);
                    t00[j] = s0[o];
                    t01[j] = s0[o + 1];
                    t10[j] = s1[o];
                    t11[j] = s1[o + 1];
                }
                #pragma unroll
                for (int j = 0; j < 4; ++j) {       // then 48 FMAs
                    const int cg = 4 * h + j;
                    float v = w00 * t00[j];
                    v = fmaf(w01, t01[j], v);
                    v = fmaf(w10, t10[j], v);
                    v = fmaf(w11, t11[j], v);
                    #pragma unroll
                    for (int og = 0; og < Og; ++og)
                        acc[og] = fmaf(v, wk[cg * Og + og], acc[og]);
                }
            }
        } else {
            #pragma unroll
            for (int cg = 0; cg < Cg; ++cg) {
                const float* xc = xg + cg * HW;
                f2u a0 = *(const f2u*)(xc + r0);
                f2u a1 = *(const f2u*)(xc + r1);
                float v = w00 * a0.x;
                v = fmaf(w01, a0.y, v);
                v = fmaf(w10, a1.x, v);
                v = fmaf(w11, a1.y, v);
                #pragma unroll
                for (int og = 0; og < Og; ++og)
                    acc[og] = fmaf(v, wk[cg * Og + og], acc[og]);
            }
        }
    }
    float* op = out + ((size_t)b * O + gu * Og) * HW + yh * W + xw;
    #pragma unroll
    for (int og = 0; og < Og; ++og) op[(size_t)og * HW] = acc[og];
}

extern "C" void kernel_launch(void* const* d_in, const int* in_sizes, int n_in,
                              void* d_out, int out_size, void* d_ws, size_t ws_size,
                              hipStream_t stream) {
    const float* input       = (const float*)d_in[0];
    const float* offset_feat = (const float*)d_in[1];
    const float* weight      = (const float*)d_in[2];
    const float* off_w       = (const float*)d_in[3];
    const float* off_b       = (const float*)d_in[4];
    float* out = (float*)d_out;

    float* offs = (float*)d_ws;
    float* w1t = offs + OFF_ELEMS;
    float* w2t = w1t + W1_ELEMS;

    transpose_weights<<<(W1_ELEMS + 255) / 256, 256, 0, stream>>>(off_w, weight, w1t, w2t);
    offset_conv<<<(B * HW) / 64, 256, 0, stream>>>(offset_feat, w1t, off_b, offs);
    deform_conv<<<B * G * TX * TY, 256, 0, stream>>>(input, offs, w2t, out);
}

// Round 16
// 97.227 us; speedup vs baseline: 1.3267x; 1.3267x over previous
//
#include <hip/hip_runtime.h>

namespace {
constexpr int B = 2, C = 72, O = 72, H = 180, W = 320;
constexpr int K = 9, G = 9, Cg = 8, Og = 8;
constexpr int OFFC = 2 * K;           // 18 offset channels
constexpr int HW = H * W;             // 57600
constexpr size_t OFF_ELEMS = (size_t)B * OFFC * HW;   // 2,073,600 floats
constexpr int W1_ELEMS = OFFC * C * 9;                // 11664
constexpr int W2_ELEMS = O * Cg * 9;                  // 5184
constexpr int ICW = C / 4;            // 18 input channels per wave

// deform tile geometry: one block = one group x (64 wide x 4 tall) pixels
constexpr int TW = 64, TH = 4;
constexpr int HALO = 2;               // R7-validated; global fallback for tail
constexpr int NR = TH + 2 * HALO;     // 8 staged rows
constexpr int NC = TW + 2 * HALO;     // 68 staged cols
constexpr int TX = W / TW;            // 5
constexpr int TY = H / TH;            // 45

typedef float f2u __attribute__((ext_vector_type(2), aligned(4)));
}

// ---------------------------------------------------------------------------
// Setup: transpose weights for contiguous wave-uniform (scalar) access.
//   w1t[ic][tap][oc]   <- off_w[oc][ic][tap]
//   w2t[g][k][cg][og]  <- weight[g*8+og][cg][k]
// ---------------------------------------------------------------------------
__global__ __launch_bounds__(256) void transpose_weights(
    const float* __restrict__ off_w,
    const float* __restrict__ weight,
    float* __restrict__ w1t,
    float* __restrict__ w2t)
{
    int i = blockIdx.x * blockDim.x + threadIdx.x;
    if (i < W1_ELEMS) {
        int oc = i % OFFC;
        int tap = (i / OFFC) % 9;
        int ic = i / (OFFC * 9);
        w1t[i] = off_w[(oc * C + ic) * 9 + tap];
    }
    if (i < W2_ELEMS) {
        int og = i % Og;
        int cg = (i / Og) % Cg;
        int k = (i / (Og * Cg)) % K;
        int g = i / (Og * Cg * K);
        w2t[i] = weight[((g * Og + og) * Cg + cg) * 9 + k];
    }
}

// ---------------------------------------------------------------------------
// Kernel 1: 3x3 conv (C=72 -> 18) + bias. 4 waves split C; LDS reduce.
// FINAL = exact R9 version (45-52us, VGPR 24, no spill). Experiment ledger:
// R10 v[9]+unroll2@(256,8) -> 32-VGPR cap spill, 259us. R12 same@uncapped
// -> 6x VALU inflation, 164us. R13 (256,4) -> 68us. R14 DPP shift -> wrong
// direction, absmax fail. R15 shfl -> ds_permute lgkmcnt serialization,
// 84us. The R9 structure + (256,8) is a sharp local optimum: incremental
// addressing keeps VALU minimal and the compiler's 24-VGPR schedule wins.
// ---------------------------------------------------------------------------
__global__ __launch_bounds__(256, 8) void offset_conv(
    const float* __restrict__ x,
    const float* __restrict__ w1t,
    const float* __restrict__ bias,
    float* __restrict__ offs)
{
    __shared__ float red[4 * 64 * OFFC];
    const int lane = threadIdx.x & 63;
    const int wave = threadIdx.x >> 6;

    const int g0 = blockIdx.x * 64;
    const int b = g0 / HW;
    const int pix = g0 - b * HW;
    const int yh = pix / W;
    const int x0b = pix - yh * W;
    const int xw = x0b + lane;

    float acc[OFFC];
    #pragma unroll
    for (int oc = 0; oc < OFFC; ++oc) acc[oc] = 0.f;

    const float* xb = x + (size_t)b * C * HW;
    const int ic0 = __builtin_amdgcn_readfirstlane(wave * ICW);

    const bool rv0 = (yh - 1) >= 0;
    const bool rv2 = (yh + 1) < H;

    #pragma unroll 3
    for (int ici = 0; ici < ICW; ++ici) {
        const int ic = ic0 + ici;
        const float* xc = xb + ic * HW;
        #pragma unroll
        for (int ky = 0; ky < 3; ++ky) {
            const int yy = yh + ky - 1;
            const bool rowv = (ky == 0) ? rv0 : (ky == 2 ? rv2 : true);
            if (!rowv) continue;
            const float* xr = xc + yy * W;
            #pragma unroll
            for (int kx = 0; kx < 3; ++kx) {
                const int xx = xw + kx - 1;
                const bool v = (xx >= 0) & (xx < W);
                const float val = v ? xr[xx] : 0.0f;
                const float* wp = w1t + (ic * 9 + ky * 3 + kx) * OFFC;
                #pragma unroll
                for (int oc = 0; oc < OFFC; ++oc)
                    acc[oc] = fmaf(val, wp[oc], acc[oc]);
            }
        }
    }

    #pragma unroll
    for (int oc = 0; oc < OFFC; ++oc)
        red[(wave * 64 + lane) * OFFC + oc] = acc[oc];
    __syncthreads();

    for (int e = threadIdx.x; e < 64 * OFFC; e += 256) {
        const int oc = e / 64;
        const int px = e - oc * 64;
        float s = bias[oc];
        #pragma unroll
        for (int w = 0; w < 4; ++w)
            s += red[(w * 64 + px) * OFFC + oc];
        offs[(size_t)b * OFFC * HW + (size_t)oc * HW + pix + px] = s;
    }
}

// ---------------------------------------------------------------------------
// Kernel 2: deformable grouped conv, LDS-staged. FINAL = exact R11 version
// (52us, VGPR 36, occ 56%): HALO=2 window + exact global fallback; div/mod-
// free staging; wave-uniform interior fast path; interior path batches 4
// channels' LDS reads into temp registers before the 48 FMAs. Rejected
// alternatives: packed-f2 builtins (R8, scalarized, +40% VALU time),
// pk_fma inline asm (R12, no gain), HALO=5 (R6, 2x LDS -> half occupancy).
// ---------------------------------------------------------------------------
__global__ __launch_bounds__(256) void deform_conv(
    const float* __restrict__ x,      // (B, C, H, W)
    const float* __restrict__ offs,   // (B, 18, H, W)
    const float* __restrict__ w2t,    // [g][k][cg][og]
    float* __restrict__ out)          // (B, O, H, W)
{
    __shared__ float sm[Cg * NR * NC];     // 17,408 B

    const int bi = blockIdx.x;
    const int tx = bi % TX;
    const int ty = (bi / TX) % TY;
    const int g  = (bi / (TX * TY)) % G;
    const int b  = bi / (TX * TY * G);

    const int lane = threadIdx.x & 63;
    const int wave = threadIdx.x >> 6;
    const int xw = tx * TW + lane;
    const int yh = ty * TH + wave;

    const int gu = __builtin_amdgcn_readfirstlane(g);
    const float* wg = w2t + gu * (K * Cg * Og);
    const float* xg = x + ((size_t)b * C + gu * Cg) * HW;
    const float* offp = offs + (size_t)b * OFFC * HW + yh * W + xw;

    // Hoist offset loads (in flight while we stage).
    float dy[K], dx[K];
    #pragma unroll
    for (int k = 0; k < K; ++k) {
        dy[k] = offp[(size_t)(2 * k) * HW];
        dx[k] = offp[(size_t)(2 * k + 1) * HW];
    }

    // Stage window [wy, wy+NR) x [wx, wx+NC) for 8 channels (div/mod-free).
    const int wy = ty * TH - HALO;
    const int wx = tx * TW - HALO;
    {
        const int sxl = min(max(wx + lane, 0), W - 1);   // per-lane, once
        #pragma unroll
        for (int i = 0; i < 16; ++i) {
            const int rowi = 4 * i + wave;               // 0..63, wave-uniform
            const int ch = rowi >> 3;
            const int rr = rowi & 7;
            const int sy = min(max(wy + rr, 0), H - 1);  // wave-uniform (SALU)
            sm[rowi * NC + lane] = xg[ch * HW + sy * W + sxl];
        }
        // tail cols 64..67: thread t -> row t>>2, col 64+(t&3)
        const int rowt = threadIdx.x >> 2;
        const int ct = 64 + (threadIdx.x & 3);
        const int cht = rowt >> 3;
        const int rrt = rowt & 7;
        const int syt = min(max(wy + rrt, 0), H - 1);
        const int sxt = min(max(wx + ct, 0), W - 1);
        sm[rowt * NC + ct] = xg[cht * HW + syt * W + sxt];
    }
    __syncthreads();

    float acc[Og];
    #pragma unroll
    for (int og = 0; og < Og; ++og) acc[og] = 0.f;

    #pragma unroll
    for (int k = 0; k < K; ++k) {
        float py = (float)(yh + k / 3 - 1) + dy[k];
        float px = (float)(xw + k % 3 - 1) + dx[k];
        float fy = floorf(py);
        float fx = floorf(px);
        int y0 = (int)fy, x0 = (int)fx;
        float wy1 = py - fy, wx1 = px - fx;
        float wy0 = 1.f - wy1, wx0 = 1.f - wx1;

        float w00, w01, w10, w11;
        int lr0, lr1, lcb, r0, r1;
        if (__all((y0 >= 0) & (y0 + 1 < H) & (x0 >= 0) & (x0 + 1 < W))) {
            // fully interior wave: no clamp/validity logic needed
            w00 = wy0 * wx0; w01 = wy0 * wx1;
            w10 = wy1 * wx0; w11 = wy1 * wx1;
            lr0 = y0 - wy; lr1 = lr0 + 1; lcb = x0 - wx;
            r0 = y0 * W + x0; r1 = r0 + W;
        } else {
            float hy0 = ((y0 >= 0) & (y0 < H)) ? wy0 : 0.f;
            float hy1 = ((y0 + 1 >= 0) & (y0 + 1 < H)) ? wy1 : 0.f;
            float gx0 = ((x0 >= 0) & (x0 < W)) ? wx0 : 0.f;
            float gx1 = ((x0 + 1 >= 0) & (x0 + 1 < W)) ? wx1 : 0.f;
            int y0c = min(max(y0, 0), H - 1);
            int y1c = min(max(y0 + 1, 0), H - 1);
            int x0c = min(max(x0, 0), W - 1);
            int x1c = min(max(x0 + 1, 0), W - 1);
            int xb2 = min(max(x0, 0), W - 2);
            float wA = (x0c == xb2 ? gx0 : 0.f) + (x1c == xb2 ? gx1 : 0.f);
            float wB = (x0c == xb2 + 1 ? gx0 : 0.f) + (x1c == xb2 + 1 ? gx1 : 0.f);
            w00 = hy0 * wA; w01 = hy0 * wB;
            w10 = hy1 * wA; w11 = hy1 * wB;
            lr0 = y0c - wy; lr1 = y1c - wy; lcb = xb2 - wx;
            r0 = y0c * W + xb2; r1 = y1c * W + xb2;
        }
        const bool inw = ((unsigned)lr0 < NR) & ((unsigned)lr1 < NR) &
                         ((unsigned)lcb < (NC - 1));
        const float* wk = wg + k * (Cg * Og);

        if (inw) {
            const float* s0 = sm + lr0 * NC + lcb;
            const float* s1 = sm + lr1 * NC + lcb;
            #pragma unroll
            for (int h = 0; h < 2; ++h) {           // 2 batches of 4 channels
                float t00[4], t01[4], t10[4], t11[4];
                #pragma unroll
                for (int j = 0; j < 4; ++j) {       // issue 16 ds_reads
                    const int o = (4 * h + j) * (NR * NC);
                    t00[j] = s0[o];
                    t01[j] = s0[o + 1];
                    t10[j] = s1[o];
                    t11[j] = s1[o + 1];
                }
                #pragma unroll
                for (int j = 0; j < 4; ++j) {       // then 48 FMAs
                    const int cg = 4 * h + j;
                    float v = w00 * t00[j];
                    v = fmaf(w01, t01[j], v);
                    v = fmaf(w10, t10[j], v);
                    v = fmaf(w11, t11[j], v);
                    #pragma unroll
                    for (int og = 0; og < Og; ++og)
                        acc[og] = fmaf(v, wk[cg * Og + og], acc[og]);
                }
            }
        } else {
            #pragma unroll
            for (int cg = 0; cg < Cg; ++cg) {
                const float* xc = xg + cg * HW;
                f2u a0 = *(const f2u*)(xc + r0);
                f2u a1 = *(const f2u*)(xc + r1);
                float v = w00 * a0.x;
                v = fmaf(w01, a0.y, v);
                v = fmaf(w10, a1.x, v);
                v = fmaf(w11, a1.y, v);
                #pragma unroll
                for (int og = 0; og < Og; ++og)
                    acc[og] = fmaf(v, wk[cg * Og + og], acc[og]);
            }
        }
    }
    float* op = out + ((size_t)b * O + gu * Og) * HW + yh * W + xw;
    #pragma unroll
    for (int og = 0; og < Og; ++og) op[(size_t)og * HW] = acc[og];
}

extern "C" void kernel_launch(void* const* d_in, const int* in_sizes, int n_in,
                              void* d_out, int out_size, void* d_ws, size_t ws_size,
                              hipStream_t stream) {
    const float* input       = (const float*)d_in[0];
    const float* offset_feat = (const float*)d_in[1];
    const float* weight      = (const float*)d_in[2];
    const float* off_w       = (const float*)d_in[3];
    const float* off_b       = (const float*)d_in[4];
    float* out = (float*)d_out;

    float* offs = (float*)d_ws;
    float* w1t = offs + OFF_ELEMS;
    float* w2t = w1t + W1_ELEMS;

    transpose_weights<<<(W1_ELEMS + 255) / 256, 256, 0, stream>>>(off_w, weight, w1t, w2t);
    offset_conv<<<(B * HW) / 64, 256, 0, stream>>>(offset_feat, w1t, off_b, offs);
    deform_conv<<<B * G * TX * TY, 256, 0, stream>>>(input, offs, w2t, out);
}